// Round 18
// baseline (804.424 us; speedup 1.0000x reference)
//
#include <hip/hip_runtime.h>
#include <hip/hip_bf16.h>
#include <math.h>

constexpr int N_NODES = 50000;
constexpr int N_EDGES = 800000;
constexpr int D  = 128;
constexpr int ED = 64;

typedef __attribute__((ext_vector_type(8))) short short8;
typedef __attribute__((ext_vector_type(4))) float f32x4;

static __device__ __forceinline__ float allsum64(float v){
#pragma unroll
  for(int off=32; off>=1; off>>=1) v += __shfl_xor(v, off, 64);
  return v;
}

static __device__ __forceinline__ short bfs(float f){
  __hip_bfloat16 h = __float2bfloat16(f);
  return *reinterpret_cast<short*>(&h);
}
static __device__ __forceinline__ float bf2f(short s){
  __hip_bfloat16 h = *reinterpret_cast<__hip_bfloat16*>(&s);
  return __bfloat162float(h);
}
static __device__ __forceinline__ float lo16(int w){ return bf2f((short)(w & 0xffff)); }
static __device__ __forceinline__ float hi16(int w){ return bf2f((short)(((unsigned)w) >> 16)); }
static __device__ __forceinline__ int pack2(float lo, float hi){
  return (int)((unsigned short)bfs(lo)) | ((int)bfs(hi) << 16);
}

template<typename T> __device__ __forceinline__ T cvt_out(float v);
template<> __device__ __forceinline__ float cvt_out<float>(float v){ return v; }
template<> __device__ __forceinline__ __hip_bfloat16 cvt_out<__hip_bfloat16>(float v){ return __float2bfloat16(v); }

// ---------------- degree count (src) + dst histogram (CSR) ----------------
__global__ void k_deg(const int* __restrict__ src, const int* __restrict__ dst,
                      int* __restrict__ deg, int* __restrict__ hist){
  int i = blockIdx.x*256 + threadIdx.x;
  if(i < N_EDGES){
    atomicAdd(&deg[src[i]], 1);
    atomicAdd(&hist[dst[i]], 1);
  }
}

// ---------------- exclusive scan over dst histogram ----------------
__global__ __launch_bounds__(1024) void k_scan(const int* __restrict__ hist,
                                               int* __restrict__ rows,
                                               int* __restrict__ cursor){
  __shared__ int part[1024];
  const int t = threadIdx.x;
  const int CH = (N_NODES + 1023) / 1024;
  int base = t*CH;
  int s = 0;
  for(int i=0;i<CH;i++){ int idx=base+i; if(idx<N_NODES) s += hist[idx]; }
  part[t] = s; __syncthreads();
  for(int off=1; off<1024; off<<=1){
    int v = (t>=off) ? part[t-off] : 0;
    __syncthreads();
    part[t] += v;
    __syncthreads();
  }
  int run = part[t] - s;
  for(int i=0;i<CH;i++){
    int idx=base+i;
    if(idx<N_NODES){ rows[idx]=run; cursor[idx]=run; run += hist[idx]; }
  }
  if(t==1023) rows[N_NODES] = run;
}

// ---------------- scatter: invp (natural->sorted) + ssrc (sorted src) ----------------
__global__ void k_scatter(const int* __restrict__ src, const int* __restrict__ dst,
                          int* __restrict__ cursor,
                          int* __restrict__ invp, int* __restrict__ ssrc){
  int e = blockIdx.x*256 + threadIdx.x;
  if(e < N_EDGES){
    int p = atomicAdd(&cursor[dst[e]], 1);
    invp[e] = p;
    ssrc[p] = src[e];
  }
}

// ---------------- x_in = x + deg_emb ; h = bf16(LN(x_in)) ----------------
__global__ __launch_bounds__(256) void k_node_prep(
    const float* __restrict__ x, const int* __restrict__ deg,
    const float* __restrict__ deg_emb, const float* __restrict__ g,
    const float* __restrict__ b, float* __restrict__ xin, short* __restrict__ h){
  int node = blockIdx.x*4 + (threadIdx.x>>6);
  int lane = threadIdx.x & 63;
  if(node >= N_NODES) return;
  int dg = deg[node]; dg = dg > 511 ? 511 : dg;
  const float* xr = x + (size_t)node*D;
  const float* er = deg_emb + (size_t)dg*D;
  float a0 = xr[lane]    + er[lane];
  float a1 = xr[lane+64] + er[lane+64];
  float* xo = xin + (size_t)node*D;
  xo[lane] = a0; xo[lane+64] = a1;
  float s  = allsum64(a0+a1);
  float s2 = allsum64(a0*a0 + a1*a1);
  float mean = s * (1.f/128.f);
  float var  = s2 * (1.f/128.f) - mean*mean;
  float rs = rsqrtf(var + 1e-5f);
  h[(size_t)node*D + lane]    = bfs((a0-mean)*rs*g[lane]    + b[lane]);
  h[(size_t)node*D + lane+64] = bfs((a1-mean)*rs*g[lane+64] + b[lane+64]);
}

// ---------------- pack Wq|Wk|Wv|Wskip into [128][512] f32 + bias ----------------
__global__ void k_pack(const float* __restrict__ Wq, const float* __restrict__ Wk,
                       const float* __restrict__ Wv, const float* __restrict__ Ws,
                       const float* __restrict__ bq, const float* __restrict__ bk,
                       const float* __restrict__ bv, const float* __restrict__ bs,
                       float* __restrict__ Wcat, float* __restrict__ bcat){
  int idx = blockIdx.x*256 + threadIdx.x;
  if(idx < D*4*D){
    int i = idx >> 9, j = idx & 511;
    int sel = j >> 7, jj = j & 127;
    const float* W = sel==0?Wq: sel==1?Wk: sel==2?Wv:Ws;
    Wcat[idx] = W[i*D + jj];
  } else if(idx < D*4*D + 4*D){
    int j = idx - D*4*D;
    int sel = j>>7, jj = j&127;
    const float* B = sel==0?bq: sel==1?bk: sel==2?bv:bs;
    bcat[j] = B[jj];
  }
}

// ---------------- bmcat = [bm[0:128] | zeros(128)] for P12 bias fold ----------------
__global__ void k_bmcat(const float* __restrict__ bm, float* __restrict__ out){
  int i = threadIdx.x;
  out[i] = (i < 128) ? bm[i] : 0.f;
}

// ---------------- pack f32 W[K][Nfull] -> bf16 MFMA-B fragments (128-col slabs) ----------------
__global__ void k_packWN(const float* __restrict__ W, short* __restrict__ out,
                         int K, int Nfull){
  int idx = blockIdx.x*256 + threadIdx.x;
  if(idx >= K*Nfull) return;
  int KC = K >> 5;
  int j  = idx & 7;
  int l  = (idx>>3) & 63;
  int cf = (idx>>9) & 7;
  int rest = idx >> 12;
  int kc = rest % KC;
  int nb = rest / KC;
  int k = kc*32 + ((l>>4)<<3) + j;
  int n = nb*128 + (cf<<4) + (l&15);
  out[idx] = bfs(W[(size_t)k*Nfull + n]);
}

// ---------------- pack Wm[0:256][128] -> fragments, nb = K-block (src/dst half) ----------------
__global__ void k_packWm12(const float* __restrict__ Wm, short* __restrict__ out){
  int idx = blockIdx.x*256 + threadIdx.x;
  if(idx >= 256*128) return;
  int j  = idx & 7;
  int l  = (idx>>3) & 63;
  int cf = (idx>>9) & 7;
  int rest = idx >> 12;       // nb*4 + kc,  KC=4
  int kc = rest & 3, nb = rest >> 2;
  int k = kc*32 + ((l>>4)<<3) + j;
  int n = (cf<<4) + (l&15);
  out[idx] = bfs(Wm[(size_t)(nb*128 + k)*128 + n]);
}

// ---------------- generic MFMA GEMM: C = act(A@B + bias) ----------------
// OMAP: 0 natural; 1 qkvs interleave; 2 C-fragment layout (l16*8+cf) for P12.
template<int ACT, int OMAP, typename OutT, typename AT>
__global__ __launch_bounds__(256) void k_gemm_mfma(
    const AT* __restrict__ A, const short* __restrict__ Wp,
    const float* __restrict__ bias,
    OutT* __restrict__ C, int M, int K, int Nfull){
  const int tid = threadIdx.x, lane = tid & 63, wid = tid >> 6;
  const int l16 = lane & 15, lg = lane >> 4;
  const int KC = K >> 5;
  const size_t rowb = (size_t)blockIdx.x*64 + wid*16;
  const int nb = blockIdx.y;
  size_t arow = rowb + l16; if(arow >= (size_t)M) arow = M-1;
  f32x4 acc[8] = {};
  const short8* Bg = ((const short8*)Wp) + (size_t)nb*KC*512 + lane;
  for(int kc=0; kc<KC; kc++){
    short8 a;
    if constexpr (sizeof(AT)==4){
      const float* ap = (const float*)A + arow*K + kc*32 + lg*8;
      float4 f0 = *(const float4*)ap;
      float4 f1 = *(const float4*)(ap+4);
      a[0]=bfs(f0.x); a[1]=bfs(f0.y); a[2]=bfs(f0.z); a[3]=bfs(f0.w);
      a[4]=bfs(f1.x); a[5]=bfs(f1.y); a[6]=bfs(f1.z); a[7]=bfs(f1.w);
    } else {
      a = *(const short8*)((const short*)A + arow*K + kc*32 + lg*8);
    }
#pragma unroll
    for(int cf=0;cf<8;cf++){
      short8 b = Bg[(kc*8+cf)*64];
      acc[cf] = __builtin_amdgcn_mfma_f32_16x16x32_bf16(a, b, acc[cf], 0, 0, 0);
    }
  }
#pragma unroll
  for(int cf=0;cf<8;cf++){
    int cIn = cf*16 + l16;
    int col = nb*128 + cIn;
    float bb = bias[col];
    int stCol;
    if(OMAP == 1){
      if(nb==0)      stCol = 2*(cIn&63) + (cIn>>6);
      else if(nb==1) stCol = 128 + 4*(cIn&63) + (cIn>>6);
      else if(nb==2) stCol = 128 + 4*(cIn&63) + 2 + (cIn>>6);
      else           stCol = 384 + 2*(cIn&63) + (cIn>>6);
    } else if(OMAP == 2){
      stCol = nb*128 + (cIn&15)*8 + (cIn>>4);
    } else stCol = col;
#pragma unroll
    for(int r=0;r<4;r++){
      size_t ro = rowb + lg*4 + r;
      if(ro < (size_t)M){
        float v = acc[cf][r] + bb;
        if(ACT == 1) v = v * 0.5f * (1.f + erff(v * 0.70710678118f));
        C[ro*Nfull + stCol] = cvt_out<OutT>(v);
      }
    }
  }
}

// ---------------- FFN2 + eu-LN fused ----------------
__global__ __launch_bounds__(256) void k_ffn2_ln(
    const short* __restrict__ A, const short* __restrict__ Wp,
    const float* __restrict__ bias, const float* __restrict__ Src,
    const float* __restrict__ g, const float* __restrict__ bv,
    float* __restrict__ xnew, short* __restrict__ xn, int M){
  const int tid = threadIdx.x, lane = tid & 63, wid = tid >> 6;
  const int l16 = lane & 15, lg = lane >> 4;
  const size_t rowb = (size_t)blockIdx.x*64 + wid*16;
  size_t arow = rowb + l16; if(arow >= (size_t)M) arow = M-1;
  f32x4 acc[8] = {};
  const short8* Bg = ((const short8*)Wp) + lane;
  for(int kc=0; kc<16; kc++){
    short8 a = *(const short8*)(A + arow*512 + kc*32 + lg*8);
#pragma unroll
    for(int cf=0;cf<8;cf++){
      short8 b = Bg[(kc*8+cf)*64];
      acc[cf] = __builtin_amdgcn_mfma_f32_16x16x32_bf16(a, b, acc[cf], 0, 0, 0);
    }
  }
  float vals[8][4];
#pragma unroll
  for(int cf=0;cf<8;cf++){
    int col = cf*16 + l16;
    float bb = bias[col];
#pragma unroll
    for(int r=0;r<4;r++){
      size_t ro = rowb + lg*4 + r; if(ro >= (size_t)M) ro = M-1;
      vals[cf][r] = acc[cf][r] + bb + Src[ro*128 + col];
    }
  }
#pragma unroll
  for(int r=0;r<4;r++){
    float s1 = 0.f, s2 = 0.f;
#pragma unroll
    for(int cf=0;cf<8;cf++){ s1 += vals[cf][r]; s2 += vals[cf][r]*vals[cf][r]; }
#pragma unroll
    for(int off=1; off<16; off<<=1){
      s1 += __shfl_xor(s1, off, 64);
      s2 += __shfl_xor(s2, off, 64);
    }
    float mean = s1 * (1.f/128.f);
    float var  = s2 * (1.f/128.f) - mean*mean;
    float rs = rsqrtf(var + 1e-5f);
    size_t ro = rowb + lg*4 + r;
    if(ro < (size_t)M){
#pragma unroll
      for(int cf=0;cf<8;cf++){
        int col = cf*16 + l16;
        xnew[ro*128 + col] = vals[cf][r];
        xn[ro*128 + col] = bfs((vals[cf][r]-mean)*rs*g[col] + bv[col]);
      }
    }
  }
}

// ---------------- e-projection NATURAL order: streaming reads, scattered stores ----------------
__global__ __launch_bounds__(256) void k_eproj_nat(
    const float* __restrict__ eattr, const int* __restrict__ invp,
    const short* __restrict__ Wep, const float* __restrict__ be,
    int* __restrict__ out /* es as int[E][64]: (col,col+64) bf16 pairs */){
  const int tid = threadIdx.x, lane = tid & 63, wid = tid >> 6;
  const int l16 = lane & 15, lg = lane >> 4;
  const size_t row = (size_t)blockIdx.x*64 + wid*16;
  const float* ga = eattr + (row + l16)*64;
  float4 f0 = *(const float4*)(ga + lg*8);
  float4 f1 = *(const float4*)(ga + lg*8 + 4);
  float4 f2 = *(const float4*)(ga + 32 + lg*8);
  float4 f3 = *(const float4*)(ga + 32 + lg*8 + 4);
  int4 pr = *(const int4*)(invp + row + lg*4);
  short8 a0, a1;
  a0[0]=bfs(f0.x); a0[1]=bfs(f0.y); a0[2]=bfs(f0.z); a0[3]=bfs(f0.w);
  a0[4]=bfs(f1.x); a0[5]=bfs(f1.y); a0[6]=bfs(f1.z); a0[7]=bfs(f1.w);
  a1[0]=bfs(f2.x); a1[1]=bfs(f2.y); a1[2]=bfs(f2.z); a1[3]=bfs(f2.w);
  a1[4]=bfs(f3.x); a1[5]=bfs(f3.y); a1[6]=bfs(f3.z); a1[7]=bfs(f3.w);
  f32x4 acc[8] = {};
  const short8* Bg = ((const short8*)Wep) + lane;
#pragma unroll
  for(int cf=0;cf<8;cf++){
    short8 b0 = Bg[cf*64];
    short8 b1 = Bg[(8+cf)*64];
    acc[cf] = __builtin_amdgcn_mfma_f32_16x16x32_bf16(a0, b0, acc[cf], 0, 0, 0);
    acc[cf] = __builtin_amdgcn_mfma_f32_16x16x32_bf16(a1, b1, acc[cf], 0, 0, 0);
  }
  int prr[4] = {pr.x, pr.y, pr.z, pr.w};
#pragma unroll
  for(int cf=0;cf<4;cf++){
    int col = cf*16 + l16;
    float blo = be[col], bhi = be[col+64];
#pragma unroll
    for(int r=0;r<4;r++)
      out[(size_t)prr[r]*64 + col] = pack2(acc[cf][r] + blo, acc[cf+4][r] + bhi);
  }
}

// ---------------- fused attention v3 + 4-edge unroll ----------------
__global__ __launch_bounds__(256) void k_attn_fused3(
    const int* __restrict__ ssrc, const int* __restrict__ rows,
    const short* __restrict__ qk, const short* __restrict__ es,
    const float* __restrict__ xin, const float* __restrict__ g,
    const float* __restrict__ b,
    float* __restrict__ xattn, short* __restrict__ hf){
  int n = blockIdx.x*4 + (threadIdx.x>>6);
  int lane = threadIdx.x & 63;
  if(n >= N_NODES) return;
  const short* qrow = qk + (size_t)n*512;
  int qw = *(const int*)(qrow + 2*lane);
  float q0 = lo16(qw), q1 = hi16(qw);
  float m0=-INFINITY, m1=-INFINITY;
  float den0=0.f, den1=0.f, acc0=0.f, acc1=0.f;
  int i = rows[n];
  const int i1 = rows[n+1];

  auto upd = [&](float a0, float a1, float v0, float v1){
    float mn0 = fmaxf(m0,a0), mn1 = fmaxf(m1,a1);
    float sc0 = __expf(m0-mn0), sc1 = __expf(m1-mn1);
    float ex0 = __expf(a0-mn0), ex1 = __expf(a1-mn1);
    den0 = den0*sc0 + ex0;       den1 = den1*sc1 + ex1;
    acc0 = acc0*sc0 + ex0*v0;    acc1 = acc1*sc1 + ex1*v1;
    m0 = mn0; m1 = mn1;
  };

  for(; i+4 <= i1; i += 4){
    int s0 = ssrc[i], s1 = ssrc[i+1], s2 = ssrc[i+2], s3 = ssrc[i+3];
    int ew0 = *(const int*)(es + (size_t)(i  )*128 + 2*lane);
    int ew1 = *(const int*)(es + (size_t)(i+1)*128 + 2*lane);
    int ew2 = *(const int*)(es + (size_t)(i+2)*128 + 2*lane);
    int ew3 = *(const int*)(es + (size_t)(i+3)*128 + 2*lane);
    int2 kv0 = *(const int2*)(qk + (size_t)s0*512 + 128 + 4*lane);
    int2 kv1 = *(const int2*)(qk + (size_t)s1*512 + 128 + 4*lane);
    int2 kv2 = *(const int2*)(qk + (size_t)s2*512 + 128 + 4*lane);
    int2 kv3 = *(const int2*)(qk + (size_t)s3*512 + 128 + 4*lane);
    float e00=lo16(ew0), e01=hi16(ew0);
    float e10=lo16(ew1), e11=hi16(ew1);
    float e20=lo16(ew2), e21=hi16(ew2);
    float e30=lo16(ew3), e31=hi16(ew3);
    float p00 = q0*(lo16(kv0.x)+e00), p01 = q1*(hi16(kv0.x)+e01);
    float p10 = q0*(lo16(kv1.x)+e10), p11 = q1*(hi16(kv1.x)+e11);
    float p20 = q0*(lo16(kv2.x)+e20), p21 = q1*(hi16(kv2.x)+e21);
    float p30 = q0*(lo16(kv3.x)+e30), p31 = q1*(hi16(kv3.x)+e31);
#pragma unroll
    for(int off=1; off<16; off<<=1){
      p00 += __shfl_xor(p00,off,64); p01 += __shfl_xor(p01,off,64);
      p10 += __shfl_xor(p10,off,64); p11 += __shfl_xor(p11,off,64);
      p20 += __shfl_xor(p20,off,64); p21 += __shfl_xor(p21,off,64);
      p30 += __shfl_xor(p30,off,64); p31 += __shfl_xor(p31,off,64);
    }
    upd(p00*0.25f, p01*0.25f, lo16(kv0.y)+e00, hi16(kv0.y)+e01);
    upd(p10*0.25f, p11*0.25f, lo16(kv1.y)+e10, hi16(kv1.y)+e11);
    upd(p20*0.25f, p21*0.25f, lo16(kv2.y)+e20, hi16(kv2.y)+e21);
    upd(p30*0.25f, p31*0.25f, lo16(kv3.y)+e30, hi16(kv3.y)+e31);
  }
  for(; i+2 <= i1; i += 2){
    int s0 = ssrc[i], s1 = ssrc[i+1];
    int ew0 = *(const int*)(es + (size_t)(i  )*128 + 2*lane);
    int ew1 = *(const int*)(es + (size_t)(i+1)*128 + 2*lane);
    int2 kv0 = *(const int2*)(qk + (size_t)s0*512 + 128 + 4*lane);
    int2 kv1 = *(const int2*)(qk + (size_t)s1*512 + 128 + 4*lane);
    float e00=lo16(ew0), e01=hi16(ew0);
    float e10=lo16(ew1), e11=hi16(ew1);
    float p00 = q0*(lo16(kv0.x)+e00), p01 = q1*(hi16(kv0.x)+e01);
    float p10 = q0*(lo16(kv1.x)+e10), p11 = q1*(hi16(kv1.x)+e11);
#pragma unroll
    for(int off=1; off<16; off<<=1){
      p00 += __shfl_xor(p00,off,64); p01 += __shfl_xor(p01,off,64);
      p10 += __shfl_xor(p10,off,64); p11 += __shfl_xor(p11,off,64);
    }
    upd(p00*0.25f, p01*0.25f, lo16(kv0.y)+e00, hi16(kv0.y)+e01);
    upd(p10*0.25f, p11*0.25f, lo16(kv1.y)+e10, hi16(kv1.y)+e11);
  }
  if(i < i1){
    int s0 = ssrc[i];
    int ew0 = *(const int*)(es + (size_t)i*128 + 2*lane);
    int2 kv0 = *(const int2*)(qk + (size_t)s0*512 + 128 + 4*lane);
    float e00=lo16(ew0), e01=hi16(ew0);
    float p00 = q0*(lo16(kv0.x)+e00), p01 = q1*(hi16(kv0.x)+e01);
#pragma unroll
    for(int off=1; off<16; off<<=1){
      p00 += __shfl_xor(p00,off,64); p01 += __shfl_xor(p01,off,64);
    }
    upd(p00*0.25f, p01*0.25f, lo16(kv0.y)+e00, hi16(kv0.y)+e01);
  }

  float o0 = acc0/(den0+1e-16f);
  float o1 = acc1/(den1+1e-16f);
  int sw = *(const int*)(qrow + 384 + 2*lane);
  size_t base = (size_t)n*128;
  float a0 = xin[base+lane]    + o0 + lo16(sw);
  float a1 = xin[base+lane+64] + o1 + hi16(sw);
  xattn[base+lane] = a0; xattn[base+lane+64] = a1;
  float s  = allsum64(a0+a1);
  float s2 = allsum64(a0*a0 + a1*a1);
  float mean = s * (1.f/128.f);
  float var  = s2 * (1.f/128.f) - mean*mean;
  float rs = rsqrtf(var + 1e-5f);
  hf[base+lane]    = bfs((a0-mean)*rs*g[lane]    + b[lane]);
  hf[base+lane+64] = bfs((a1-mean)*rs*g[lane+64] + b[lane+64]);
}

// ---------------- EdgeUpdate v10: 16 edges/wave (occupancy-optimized) ----------------
// Same structure as v9 but narrow: acc[8], LDS tile [16][68] f32 per wave,
// hoisted P12 gathers, fast epilogue. Higher resident-wave count hides latency.
__global__ __launch_bounds__(256) void k_edge_mfma10(
    const int* __restrict__ src, const int* __restrict__ dst,
    const short* __restrict__ P12, const float* __restrict__ ea,
    const short* __restrict__ Wmep,
    const float* __restrict__ eg, const float* __restrict__ ebv,
    float* __restrict__ out){
  __shared__ float eas[4][16*68];
  const int tid = threadIdx.x, lane = tid & 63, wid = tid >> 6;
  const int l16 = lane & 15, lg = lane >> 4;
  const size_t e0 = (size_t)blockIdx.x*64 + wid*16;
  const int ko = lg*8;
  f32x4 acc[8] = {};
  const short8* Bg = ((const short8*)Wmep) + lane;
  float* myl = eas[wid];

  // hoisted P12 fragment gathers (MLP)
  short8 p1v[4], p2v[4];
#pragma unroll
  for(int r=0;r<4;r++){
    size_t erow = e0 + lg*4 + r;
    int sE = src[erow], dE = dst[erow];
    p1v[r] = *(const short8*)(P12 + (size_t)sE*256 + l16*8);
    p2v[r] = *(const short8*)(P12 + (size_t)dE*256 + 128 + l16*8);
  }

  // A-build: single global read of ea tile; stage f32 to LDS + cvt to fragments
#pragma unroll
  for(int kc=0; kc<2; kc++){
    const float* ap = ea + (e0 + l16)*64 + kc*32 + ko;
    float4 f0 = *(const float4*)ap;
    float4 f1 = *(const float4*)(ap+4);
    float* lp = &myl[l16*68 + kc*32 + ko];
    *(float4*)lp     = f0;
    *(float4*)(lp+4) = f1;
    short8 a;
    a[0]=bfs(f0.x); a[1]=bfs(f0.y); a[2]=bfs(f0.z); a[3]=bfs(f0.w);
    a[4]=bfs(f1.x); a[5]=bfs(f1.y); a[6]=bfs(f1.z); a[7]=bfs(f1.w);
#pragma unroll
    for(int cf=0;cf<8;cf++){
      short8 b = Bg[(kc*8+cf)*64];
      acc[cf] = __builtin_amdgcn_mfma_f32_16x16x32_bf16(a, b, acc[cf], 0, 0, 0);
    }
  }

#pragma unroll
  for(int r=0;r<4;r++)
#pragma unroll
    for(int cf=0;cf<8;cf++)
      acc[cf][r] += bf2f(p1v[r][cf]) + bf2f(p2v[r][cf]);

  // epilogue ea values from LDS
  float eav[4][4];
#pragma unroll
  for(int r=0;r<4;r++)
#pragma unroll
    for(int cf=0;cf<4;cf++)
      eav[r][cf] = myl[(lg*4 + r)*68 + cf*16 + l16];

  float egc[4], ebc[4];
#pragma unroll
  for(int cf=0;cf<4;cf++){
    int col = cf*16 + l16;
    egc[cf] = eg[col];
    ebc[cf] = ebv[col];
  }
#pragma unroll
  for(int r=0;r<4;r++){
    size_t erow = e0 + lg*4 + r;
    float u[4];
    float s1 = 0.f, s2 = 0.f;
#pragma unroll
    for(int cf=0;cf<4;cf++){
      float dlt = fmaxf(0.f, acc[cf][r]);
      float gt  = fmaxf(0.f, acc[cf+4][r]);
      float sig = __builtin_amdgcn_rcpf(1.f + __expf(-gt));
      float uu = eav[r][cf] + dlt * sig;
      u[cf] = uu; s1 += uu; s2 += uu*uu;
    }
#pragma unroll
    for(int off=1; off<16; off<<=1){
      s1 += __shfl_xor(s1, off, 64);
      s2 += __shfl_xor(s2, off, 64);
    }
    float mean = s1 * (1.f/64.f);
    float var  = s2 * (1.f/64.f) - mean*mean;
    float rs = rsqrtf(var + 1e-5f);
#pragma unroll
    for(int cf=0;cf<4;cf++)
      out[erow*64 + cf*16 + l16] = (u[cf]-mean)*rs*egc[cf] + ebc[cf];
  }
}

extern "C" void kernel_launch(void* const* d_in, const int* in_sizes, int n_in,
                              void* d_out, int out_size, void* d_ws, size_t ws_size,
                              hipStream_t stream){
  const float* x       = (const float*)d_in[0];
  const int*   eidx    = (const int*)d_in[1];
  const float* eattr   = (const float*)d_in[2];
  const float* deg_emb = (const float*)d_in[3];
  const float* ln_g = (const float*)d_in[4];
  const float* ln_b = (const float*)d_in[5];
  const float* Wq = (const float*)d_in[6];  const float* bq = (const float*)d_in[7];
  const float* Wk = (const float*)d_in[8];  const float* bk = (const float*)d_in[9];
  const float* Wv = (const float*)d_in[10]; const float* bv = (const float*)d_in[11];
  const float* We = (const float*)d_in[12]; const float* be = (const float*)d_in[13];
  const float* Ws = (const float*)d_in[14]; const float* bs = (const float*)d_in[15];
  const float* W1 = (const float*)d_in[16]; const float* b1 = (const float*)d_in[17];
  const float* W2 = (const float*)d_in[18]; const float* b2 = (const float*)d_in[19];
  const float* eug = (const float*)d_in[20]; const float* eub = (const float*)d_in[21];
  const float* Wm = (const float*)d_in[22]; const float* bm = (const float*)d_in[23];
  const float* eg = (const float*)d_in[24]; const float* eb = (const float*)d_in[25];
  (void)in_sizes; (void)n_in; (void)out_size; (void)ws_size;

  const int* src = eidx;
  const int* dst = eidx + N_EDGES;

  float* ws = (float*)d_ws;
  size_t o = 0;
  auto alloc = [&](size_t n){ size_t r = o; o += (n + 63) & ~(size_t)63; return r; };
  size_t o_deg   = alloc(N_NODES);                 // int, memset
  size_t o_hist  = alloc(N_NODES);                 // int, memset
  size_t zero_f  = o;
  size_t o_rows  = alloc(N_NODES+1);               // int
  size_t o_cur   = alloc(N_NODES);                 // int
  size_t o_invp  = alloc(N_EDGES);                 // int: natural -> sorted position
  size_t o_ssrc  = alloc(N_EDGES);                 // int
  size_t o_attn  = alloc((size_t)N_NODES*D);       // x_attn f32
  size_t o_xin   = alloc((size_t)N_NODES*D);       // x_in f32; xn(bf16) reuses later
  size_t o_h     = alloc((size_t)N_NODES*D/2);     // h bf16 -> hf bf16
  size_t o_qkv16 = alloc((size_t)N_NODES*256);     // qkvs bf16 [N,512]; t1 reuses
  size_t o_p12   = alloc((size_t)N_NODES*128);     // P12 bf16 [N,256]
  size_t o_wcat  = alloc((size_t)D*4*D);
  size_t o_bcat  = alloc(4*D);
  size_t o_bmcat = alloc(256);
  size_t o_wqp   = alloc((size_t)128*512/2);
  size_t o_w1p   = alloc((size_t)128*512/2);
  size_t o_w2p   = alloc((size_t)512*128/2);
  size_t o_wm12  = alloc((size_t)256*128/2);       // Wm[0:256] packed
  size_t o_wmep  = alloc((size_t)64*128/2);        // Wm[256:320] packed
  size_t o_wep   = alloc((size_t)64*128/2);        // We packed

  float* xnew_out = (float*)d_out;                          // [N,128]
  float* ea_out   = xnew_out + (size_t)N_NODES*D;           // [E,64]
  short* es = (short*)ea_out;                               // sorted interleaved e-proj

  hipMemsetAsync(d_ws, 0, zero_f*sizeof(float), stream);

  k_deg<<<(N_EDGES+255)/256, 256, 0, stream>>>(src, dst, (int*)(ws+o_deg),
                                               (int*)(ws+o_hist));
  k_scan<<<1, 1024, 0, stream>>>((int*)(ws+o_hist), (int*)(ws+o_rows),
                                 (int*)(ws+o_cur));
  k_scatter<<<(N_EDGES+255)/256, 256, 0, stream>>>(src, dst, (int*)(ws+o_cur),
                                                   (int*)(ws+o_invp),
                                                   (int*)(ws+o_ssrc));
  k_node_prep<<<N_NODES/4, 256, 0, stream>>>(x, (int*)(ws+o_deg), deg_emb, ln_g, ln_b,
                                             ws+o_xin, (short*)(ws+o_h));
  k_pack<<<(D*4*D + 4*D + 255)/256, 256, 0, stream>>>(Wq,Wk,Wv,Ws, bq,bk,bv,bs,
                                                      ws+o_wcat, ws+o_bcat);
  k_bmcat<<<1, 256, 0, stream>>>(bm, ws+o_bmcat);
  k_packWN<<<256, 256, 0, stream>>>(ws+o_wcat, (short*)(ws+o_wqp), 128, 512);
  k_packWN<<<256, 256, 0, stream>>>(W1, (short*)(ws+o_w1p), 128, 512);
  k_packWN<<<256, 256, 0, stream>>>(W2, (short*)(ws+o_w2p), 512, 128);
  k_packWm12<<<128, 256, 0, stream>>>(Wm, (short*)(ws+o_wm12));
  k_packWN<<<32,  256, 0, stream>>>(Wm + 256*128, (short*)(ws+o_wmep), 64, 128);
  k_packWN<<<32,  256, 0, stream>>>(We, (short*)(ws+o_wep), 64, 128);
  {
    dim3 g((N_NODES+63)/64, 4);    // qkvs = bf16(h @ Wcat + bcat), interleaved store
    k_gemm_mfma<0,1,__hip_bfloat16,short><<<g,256,0,stream>>>(
        (const short*)(ws+o_h), (const short*)(ws+o_wqp), ws+o_bcat,
        (__hip_bfloat16*)(ws+o_qkv16), N_NODES, 128, 512);
  }
  k_eproj_nat<<<N_EDGES/64, 256, 0, stream>>>(eattr, (const int*)(ws+o_invp),
                                              (const short*)(ws+o_wep), be,
                                              (int*)es);
  k_attn_fused3<<<(N_NODES+3)/4, 256, 0, stream>>>((const int*)(ws+o_ssrc),
                                                   (int*)(ws+o_rows),
                                                   (const short*)(ws+o_qkv16), es,
                                                   ws+o_xin, ln_g, ln_b,
                                                   ws+o_attn, (short*)(ws+o_h));
  {
    dim3 g((N_NODES+63)/64, 4);    // t1 = bf16(gelu(hf @ W1 + b1)), natural store
    k_gemm_mfma<1,0,__hip_bfloat16,short><<<g,256,0,stream>>>(
        (const short*)(ws+o_h), (const short*)(ws+o_w1p), b1,
        (__hip_bfloat16*)(ws+o_qkv16), N_NODES, 128, 512);
  }
  {
    dim3 g((N_NODES+63)/64);       // x_new + fused eu-LN -> xn bf16 (o_xin)
    k_ffn2_ln<<<g,256,0,stream>>>(
        (const short*)(ws+o_qkv16), (const short*)(ws+o_w2p), b2, ws+o_attn,
        eug, eub, xnew_out, (short*)(ws+o_xin), N_NODES);
  }
  {
    dim3 g((N_NODES+63)/64, 2);    // P12 = bf16(xn @ [Wm_src|Wm_dst] + bmcat), fragment layout
    k_gemm_mfma<0,2,__hip_bfloat16,short><<<g,256,0,stream>>>(
        (const short*)(ws+o_xin), (const short*)(ws+o_wm12), ws+o_bmcat,
        (__hip_bfloat16*)(ws+o_p12), N_NODES, 128, 256);
  }
  k_edge_mfma10<<<N_EDGES/64, 256, 0, stream>>>(src, dst, (const short*)(ws+o_p12),
                                                eattr, (const short*)(ws+o_wmep),
                                                eg, eb, ea_out);
}

// Round 19
// 784.857 us; speedup vs baseline: 1.0249x; 1.0249x over previous
//
#include <hip/hip_runtime.h>
#include <hip/hip_bf16.h>
#include <math.h>

constexpr int N_NODES = 50000;
constexpr int N_EDGES = 800000;
constexpr int D  = 128;
constexpr int ED = 64;

typedef __attribute__((ext_vector_type(8))) short short8;
typedef __attribute__((ext_vector_type(4))) float f32x4;

static __device__ __forceinline__ float allsum64(float v){
#pragma unroll
  for(int off=32; off>=1; off>>=1) v += __shfl_xor(v, off, 64);
  return v;
}

static __device__ __forceinline__ short bfs(float f){
  __hip_bfloat16 h = __float2bfloat16(f);
  return *reinterpret_cast<short*>(&h);
}
static __device__ __forceinline__ float bf2f(short s){
  __hip_bfloat16 h = *reinterpret_cast<__hip_bfloat16*>(&s);
  return __bfloat162float(h);
}
static __device__ __forceinline__ float lo16(int w){ return bf2f((short)(w & 0xffff)); }
static __device__ __forceinline__ float hi16(int w){ return bf2f((short)(((unsigned)w) >> 16)); }
static __device__ __forceinline__ int pack2(float lo, float hi){
  return (int)((unsigned short)bfs(lo)) | ((int)bfs(hi) << 16);
}

template<typename T> __device__ __forceinline__ T cvt_out(float v);
template<> __device__ __forceinline__ float cvt_out<float>(float v){ return v; }
template<> __device__ __forceinline__ __hip_bfloat16 cvt_out<__hip_bfloat16>(float v){ return __float2bfloat16(v); }

// ---------------- degree count (src) + dst histogram (CSR) ----------------
__global__ void k_deg(const int* __restrict__ src, const int* __restrict__ dst,
                      int* __restrict__ deg, int* __restrict__ hist){
  int i = blockIdx.x*256 + threadIdx.x;
  if(i < N_EDGES){
    atomicAdd(&deg[src[i]], 1);
    atomicAdd(&hist[dst[i]], 1);
  }
}

// ---------------- exclusive scan over dst histogram ----------------
__global__ __launch_bounds__(1024) void k_scan(const int* __restrict__ hist,
                                               int* __restrict__ rows,
                                               int* __restrict__ cursor){
  __shared__ int part[1024];
  const int t = threadIdx.x;
  const int CH = (N_NODES + 1023) / 1024;
  int base = t*CH;
  int s = 0;
  for(int i=0;i<CH;i++){ int idx=base+i; if(idx<N_NODES) s += hist[idx]; }
  part[t] = s; __syncthreads();
  for(int off=1; off<1024; off<<=1){
    int v = (t>=off) ? part[t-off] : 0;
    __syncthreads();
    part[t] += v;
    __syncthreads();
  }
  int run = part[t] - s;
  for(int i=0;i<CH;i++){
    int idx=base+i;
    if(idx<N_NODES){ rows[idx]=run; cursor[idx]=run; run += hist[idx]; }
  }
  if(t==1023) rows[N_NODES] = run;
}

// ---------------- scatter: invp (natural->sorted) + ssrc (sorted src) ----------------
__global__ void k_scatter(const int* __restrict__ src, const int* __restrict__ dst,
                          int* __restrict__ cursor,
                          int* __restrict__ invp, int* __restrict__ ssrc){
  int e = blockIdx.x*256 + threadIdx.x;
  if(e < N_EDGES){
    int p = atomicAdd(&cursor[dst[e]], 1);
    invp[e] = p;
    ssrc[p] = src[e];
  }
}

// ---------------- x_in = x + deg_emb ; h = bf16(LN(x_in)) ----------------
__global__ __launch_bounds__(256) void k_node_prep(
    const float* __restrict__ x, const int* __restrict__ deg,
    const float* __restrict__ deg_emb, const float* __restrict__ g,
    const float* __restrict__ b, float* __restrict__ xin, short* __restrict__ h){
  int node = blockIdx.x*4 + (threadIdx.x>>6);
  int lane = threadIdx.x & 63;
  if(node >= N_NODES) return;
  int dg = deg[node]; dg = dg > 511 ? 511 : dg;
  const float* xr = x + (size_t)node*D;
  const float* er = deg_emb + (size_t)dg*D;
  float a0 = xr[lane]    + er[lane];
  float a1 = xr[lane+64] + er[lane+64];
  float* xo = xin + (size_t)node*D;
  xo[lane] = a0; xo[lane+64] = a1;
  float s  = allsum64(a0+a1);
  float s2 = allsum64(a0*a0 + a1*a1);
  float mean = s * (1.f/128.f);
  float var  = s2 * (1.f/128.f) - mean*mean;
  float rs = rsqrtf(var + 1e-5f);
  h[(size_t)node*D + lane]    = bfs((a0-mean)*rs*g[lane]    + b[lane]);
  h[(size_t)node*D + lane+64] = bfs((a1-mean)*rs*g[lane+64] + b[lane+64]);
}

// ---------------- pack Wq|Wk|Wv|Wskip into [128][512] f32 + bias ----------------
__global__ void k_pack(const float* __restrict__ Wq, const float* __restrict__ Wk,
                       const float* __restrict__ Wv, const float* __restrict__ Ws,
                       const float* __restrict__ bq, const float* __restrict__ bk,
                       const float* __restrict__ bv, const float* __restrict__ bs,
                       float* __restrict__ Wcat, float* __restrict__ bcat){
  int idx = blockIdx.x*256 + threadIdx.x;
  if(idx < D*4*D){
    int i = idx >> 9, j = idx & 511;
    int sel = j >> 7, jj = j & 127;
    const float* W = sel==0?Wq: sel==1?Wk: sel==2?Wv:Ws;
    Wcat[idx] = W[i*D + jj];
  } else if(idx < D*4*D + 4*D){
    int j = idx - D*4*D;
    int sel = j>>7, jj = j&127;
    const float* B = sel==0?bq: sel==1?bk: sel==2?bv:bs;
    bcat[j] = B[jj];
  }
}

// ---------------- bmcat = [bm[0:128] | zeros(128)] for P12 bias fold ----------------
__global__ void k_bmcat(const float* __restrict__ bm, float* __restrict__ out){
  int i = threadIdx.x;
  out[i] = (i < 128) ? bm[i] : 0.f;
}

// ---------------- pack f32 W[K][Nfull] -> bf16 MFMA-B fragments (128-col slabs) ----------------
__global__ void k_packWN(const float* __restrict__ W, short* __restrict__ out,
                         int K, int Nfull){
  int idx = blockIdx.x*256 + threadIdx.x;
  if(idx >= K*Nfull) return;
  int KC = K >> 5;
  int j  = idx & 7;
  int l  = (idx>>3) & 63;
  int cf = (idx>>9) & 7;
  int rest = idx >> 12;
  int kc = rest % KC;
  int nb = rest / KC;
  int k = kc*32 + ((l>>4)<<3) + j;
  int n = nb*128 + (cf<<4) + (l&15);
  out[idx] = bfs(W[(size_t)k*Nfull + n]);
}

// ---------------- pack Wm[0:256][128] -> fragments, nb = K-block (src/dst half) ----------------
__global__ void k_packWm12(const float* __restrict__ Wm, short* __restrict__ out){
  int idx = blockIdx.x*256 + threadIdx.x;
  if(idx >= 256*128) return;
  int j  = idx & 7;
  int l  = (idx>>3) & 63;
  int cf = (idx>>9) & 7;
  int rest = idx >> 12;       // nb*4 + kc,  KC=4
  int kc = rest & 3, nb = rest >> 2;
  int k = kc*32 + ((l>>4)<<3) + j;
  int n = (cf<<4) + (l&15);
  out[idx] = bfs(Wm[(size_t)(nb*128 + k)*128 + n]);
}

// ---------------- generic MFMA GEMM: C = act(A@B + bias) ----------------
// OMAP: 0 natural; 1 qkvs interleave; 2 C-fragment layout (l16*8+cf) for P12.
template<int ACT, int OMAP, typename OutT, typename AT>
__global__ __launch_bounds__(256) void k_gemm_mfma(
    const AT* __restrict__ A, const short* __restrict__ Wp,
    const float* __restrict__ bias,
    OutT* __restrict__ C, int M, int K, int Nfull){
  const int tid = threadIdx.x, lane = tid & 63, wid = tid >> 6;
  const int l16 = lane & 15, lg = lane >> 4;
  const int KC = K >> 5;
  const size_t rowb = (size_t)blockIdx.x*64 + wid*16;
  const int nb = blockIdx.y;
  size_t arow = rowb + l16; if(arow >= (size_t)M) arow = M-1;
  f32x4 acc[8] = {};
  const short8* Bg = ((const short8*)Wp) + (size_t)nb*KC*512 + lane;
  for(int kc=0; kc<KC; kc++){
    short8 a;
    if constexpr (sizeof(AT)==4){
      const float* ap = (const float*)A + arow*K + kc*32 + lg*8;
      float4 f0 = *(const float4*)ap;
      float4 f1 = *(const float4*)(ap+4);
      a[0]=bfs(f0.x); a[1]=bfs(f0.y); a[2]=bfs(f0.z); a[3]=bfs(f0.w);
      a[4]=bfs(f1.x); a[5]=bfs(f1.y); a[6]=bfs(f1.z); a[7]=bfs(f1.w);
    } else {
      a = *(const short8*)((const short*)A + arow*K + kc*32 + lg*8);
    }
#pragma unroll
    for(int cf=0;cf<8;cf++){
      short8 b = Bg[(kc*8+cf)*64];
      acc[cf] = __builtin_amdgcn_mfma_f32_16x16x32_bf16(a, b, acc[cf], 0, 0, 0);
    }
  }
#pragma unroll
  for(int cf=0;cf<8;cf++){
    int cIn = cf*16 + l16;
    int col = nb*128 + cIn;
    float bb = bias[col];
    int stCol;
    if(OMAP == 1){
      if(nb==0)      stCol = 2*(cIn&63) + (cIn>>6);
      else if(nb==1) stCol = 128 + 4*(cIn&63) + (cIn>>6);
      else if(nb==2) stCol = 128 + 4*(cIn&63) + 2 + (cIn>>6);
      else           stCol = 384 + 2*(cIn&63) + (cIn>>6);
    } else if(OMAP == 2){
      stCol = nb*128 + (cIn&15)*8 + (cIn>>4);
    } else stCol = col;
#pragma unroll
    for(int r=0;r<4;r++){
      size_t ro = rowb + lg*4 + r;
      if(ro < (size_t)M){
        float v = acc[cf][r] + bb;
        if(ACT == 1) v = v * 0.5f * (1.f + erff(v * 0.70710678118f));
        C[ro*Nfull + stCol] = cvt_out<OutT>(v);
      }
    }
  }
}

// ---------------- FFN2 + eu-LN fused ----------------
__global__ __launch_bounds__(256) void k_ffn2_ln(
    const short* __restrict__ A, const short* __restrict__ Wp,
    const float* __restrict__ bias, const float* __restrict__ Src,
    const float* __restrict__ g, const float* __restrict__ bv,
    float* __restrict__ xnew, short* __restrict__ xn, int M){
  const int tid = threadIdx.x, lane = tid & 63, wid = tid >> 6;
  const int l16 = lane & 15, lg = lane >> 4;
  const size_t rowb = (size_t)blockIdx.x*64 + wid*16;
  size_t arow = rowb + l16; if(arow >= (size_t)M) arow = M-1;
  f32x4 acc[8] = {};
  const short8* Bg = ((const short8*)Wp) + lane;
  for(int kc=0; kc<16; kc++){
    short8 a = *(const short8*)(A + arow*512 + kc*32 + lg*8);
#pragma unroll
    for(int cf=0;cf<8;cf++){
      short8 b = Bg[(kc*8+cf)*64];
      acc[cf] = __builtin_amdgcn_mfma_f32_16x16x32_bf16(a, b, acc[cf], 0, 0, 0);
    }
  }
  float vals[8][4];
#pragma unroll
  for(int cf=0;cf<8;cf++){
    int col = cf*16 + l16;
    float bb = bias[col];
#pragma unroll
    for(int r=0;r<4;r++){
      size_t ro = rowb + lg*4 + r; if(ro >= (size_t)M) ro = M-1;
      vals[cf][r] = acc[cf][r] + bb + Src[ro*128 + col];
    }
  }
#pragma unroll
  for(int r=0;r<4;r++){
    float s1 = 0.f, s2 = 0.f;
#pragma unroll
    for(int cf=0;cf<8;cf++){ s1 += vals[cf][r]; s2 += vals[cf][r]*vals[cf][r]; }
#pragma unroll
    for(int off=1; off<16; off<<=1){
      s1 += __shfl_xor(s1, off, 64);
      s2 += __shfl_xor(s2, off, 64);
    }
    float mean = s1 * (1.f/128.f);
    float var  = s2 * (1.f/128.f) - mean*mean;
    float rs = rsqrtf(var + 1e-5f);
    size_t ro = rowb + lg*4 + r;
    if(ro < (size_t)M){
#pragma unroll
      for(int cf=0;cf<8;cf++){
        int col = cf*16 + l16;
        xnew[ro*128 + col] = vals[cf][r];
        xn[ro*128 + col] = bfs((vals[cf][r]-mean)*rs*g[col] + bv[col]);
      }
    }
  }
}

// ---------------- e-projection NATURAL order: streaming reads, scattered stores ----------------
__global__ __launch_bounds__(256) void k_eproj_nat(
    const float* __restrict__ eattr, const int* __restrict__ invp,
    const short* __restrict__ Wep, const float* __restrict__ be,
    int* __restrict__ out /* es as int[E][64]: (col,col+64) bf16 pairs */){
  const int tid = threadIdx.x, lane = tid & 63, wid = tid >> 6;
  const int l16 = lane & 15, lg = lane >> 4;
  const size_t row = (size_t)blockIdx.x*64 + wid*16;
  const float* ga = eattr + (row + l16)*64;
  float4 f0 = *(const float4*)(ga + lg*8);
  float4 f1 = *(const float4*)(ga + lg*8 + 4);
  float4 f2 = *(const float4*)(ga + 32 + lg*8);
  float4 f3 = *(const float4*)(ga + 32 + lg*8 + 4);
  int4 pr = *(const int4*)(invp + row + lg*4);
  short8 a0, a1;
  a0[0]=bfs(f0.x); a0[1]=bfs(f0.y); a0[2]=bfs(f0.z); a0[3]=bfs(f0.w);
  a0[4]=bfs(f1.x); a0[5]=bfs(f1.y); a0[6]=bfs(f1.z); a0[7]=bfs(f1.w);
  a1[0]=bfs(f2.x); a1[1]=bfs(f2.y); a1[2]=bfs(f2.z); a1[3]=bfs(f2.w);
  a1[4]=bfs(f3.x); a1[5]=bfs(f3.y); a1[6]=bfs(f3.z); a1[7]=bfs(f3.w);
  f32x4 acc[8] = {};
  const short8* Bg = ((const short8*)Wep) + lane;
#pragma unroll
  for(int cf=0;cf<8;cf++){
    short8 b0 = Bg[cf*64];
    short8 b1 = Bg[(8+cf)*64];
    acc[cf] = __builtin_amdgcn_mfma_f32_16x16x32_bf16(a0, b0, acc[cf], 0, 0, 0);
    acc[cf] = __builtin_amdgcn_mfma_f32_16x16x32_bf16(a1, b1, acc[cf], 0, 0, 0);
  }
  int prr[4] = {pr.x, pr.y, pr.z, pr.w};
#pragma unroll
  for(int cf=0;cf<4;cf++){
    int col = cf*16 + l16;
    float blo = be[col], bhi = be[col+64];
#pragma unroll
    for(int r=0;r<4;r++)
      out[(size_t)prr[r]*64 + col] = pack2(acc[cf][r] + blo, acc[cf+4][r] + bhi);
  }
}

// ---------------- fused attention v3 + 4-edge unroll ----------------
__global__ __launch_bounds__(256) void k_attn_fused3(
    const int* __restrict__ ssrc, const int* __restrict__ rows,
    const short* __restrict__ qk, const short* __restrict__ es,
    const float* __restrict__ xin, const float* __restrict__ g,
    const float* __restrict__ b,
    float* __restrict__ xattn, short* __restrict__ hf){
  int n = blockIdx.x*4 + (threadIdx.x>>6);
  int lane = threadIdx.x & 63;
  if(n >= N_NODES) return;
  const short* qrow = qk + (size_t)n*512;
  int qw = *(const int*)(qrow + 2*lane);
  float q0 = lo16(qw), q1 = hi16(qw);
  float m0=-INFINITY, m1=-INFINITY;
  float den0=0.f, den1=0.f, acc0=0.f, acc1=0.f;
  int i = rows[n];
  const int i1 = rows[n+1];

  auto upd = [&](float a0, float a1, float v0, float v1){
    float mn0 = fmaxf(m0,a0), mn1 = fmaxf(m1,a1);
    float sc0 = __expf(m0-mn0), sc1 = __expf(m1-mn1);
    float ex0 = __expf(a0-mn0), ex1 = __expf(a1-mn1);
    den0 = den0*sc0 + ex0;       den1 = den1*sc1 + ex1;
    acc0 = acc0*sc0 + ex0*v0;    acc1 = acc1*sc1 + ex1*v1;
    m0 = mn0; m1 = mn1;
  };

  for(; i+4 <= i1; i += 4){
    int s0 = ssrc[i], s1 = ssrc[i+1], s2 = ssrc[i+2], s3 = ssrc[i+3];
    int ew0 = *(const int*)(es + (size_t)(i  )*128 + 2*lane);
    int ew1 = *(const int*)(es + (size_t)(i+1)*128 + 2*lane);
    int ew2 = *(const int*)(es + (size_t)(i+2)*128 + 2*lane);
    int ew3 = *(const int*)(es + (size_t)(i+3)*128 + 2*lane);
    int2 kv0 = *(const int2*)(qk + (size_t)s0*512 + 128 + 4*lane);
    int2 kv1 = *(const int2*)(qk + (size_t)s1*512 + 128 + 4*lane);
    int2 kv2 = *(const int2*)(qk + (size_t)s2*512 + 128 + 4*lane);
    int2 kv3 = *(const int2*)(qk + (size_t)s3*512 + 128 + 4*lane);
    float e00=lo16(ew0), e01=hi16(ew0);
    float e10=lo16(ew1), e11=hi16(ew1);
    float e20=lo16(ew2), e21=hi16(ew2);
    float e30=lo16(ew3), e31=hi16(ew3);
    float p00 = q0*(lo16(kv0.x)+e00), p01 = q1*(hi16(kv0.x)+e01);
    float p10 = q0*(lo16(kv1.x)+e10), p11 = q1*(hi16(kv1.x)+e11);
    float p20 = q0*(lo16(kv2.x)+e20), p21 = q1*(hi16(kv2.x)+e21);
    float p30 = q0*(lo16(kv3.x)+e30), p31 = q1*(hi16(kv3.x)+e31);
#pragma unroll
    for(int off=1; off<16; off<<=1){
      p00 += __shfl_xor(p00,off,64); p01 += __shfl_xor(p01,off,64);
      p10 += __shfl_xor(p10,off,64); p11 += __shfl_xor(p11,off,64);
      p20 += __shfl_xor(p20,off,64); p21 += __shfl_xor(p21,off,64);
      p30 += __shfl_xor(p30,off,64); p31 += __shfl_xor(p31,off,64);
    }
    upd(p00*0.25f, p01*0.25f, lo16(kv0.y)+e00, hi16(kv0.y)+e01);
    upd(p10*0.25f, p11*0.25f, lo16(kv1.y)+e10, hi16(kv1.y)+e11);
    upd(p20*0.25f, p21*0.25f, lo16(kv2.y)+e20, hi16(kv2.y)+e21);
    upd(p30*0.25f, p31*0.25f, lo16(kv3.y)+e30, hi16(kv3.y)+e31);
  }
  for(; i+2 <= i1; i += 2){
    int s0 = ssrc[i], s1 = ssrc[i+1];
    int ew0 = *(const int*)(es + (size_t)(i  )*128 + 2*lane);
    int ew1 = *(const int*)(es + (size_t)(i+1)*128 + 2*lane);
    int2 kv0 = *(const int2*)(qk + (size_t)s0*512 + 128 + 4*lane);
    int2 kv1 = *(const int2*)(qk + (size_t)s1*512 + 128 + 4*lane);
    float e00=lo16(ew0), e01=hi16(ew0);
    float e10=lo16(ew1), e11=hi16(ew1);
    float p00 = q0*(lo16(kv0.x)+e00), p01 = q1*(hi16(kv0.x)+e01);
    float p10 = q0*(lo16(kv1.x)+e10), p11 = q1*(hi16(kv1.x)+e11);
#pragma unroll
    for(int off=1; off<16; off<<=1){
      p00 += __shfl_xor(p00,off,64); p01 += __shfl_xor(p01,off,64);
      p10 += __shfl_xor(p10,off,64); p11 += __shfl_xor(p11,off,64);
    }
    upd(p00*0.25f, p01*0.25f, lo16(kv0.y)+e00, hi16(kv0.y)+e01);
    upd(p10*0.25f, p11*0.25f, lo16(kv1.y)+e10, hi16(kv1.y)+e11);
  }
  if(i < i1){
    int s0 = ssrc[i];
    int ew0 = *(const int*)(es + (size_t)i*128 + 2*lane);
    int2 kv0 = *(const int2*)(qk + (size_t)s0*512 + 128 + 4*lane);
    float e00=lo16(ew0), e01=hi16(ew0);
    float p00 = q0*(lo16(kv0.x)+e00), p01 = q1*(hi16(kv0.x)+e01);
#pragma unroll
    for(int off=1; off<16; off<<=1){
      p00 += __shfl_xor(p00,off,64); p01 += __shfl_xor(p01,off,64);
    }
    upd(p00*0.25f, p01*0.25f, lo16(kv0.y)+e00, hi16(kv0.y)+e01);
  }

  float o0 = acc0/(den0+1e-16f);
  float o1 = acc1/(den1+1e-16f);
  int sw = *(const int*)(qrow + 384 + 2*lane);
  size_t base = (size_t)n*128;
  float a0 = xin[base+lane]    + o0 + lo16(sw);
  float a1 = xin[base+lane+64] + o1 + hi16(sw);
  xattn[base+lane] = a0; xattn[base+lane+64] = a1;
  float s  = allsum64(a0+a1);
  float s2 = allsum64(a0*a0 + a1*a1);
  float mean = s * (1.f/128.f);
  float var  = s2 * (1.f/128.f) - mean*mean;
  float rs = rsqrtf(var + 1e-5f);
  hf[base+lane]    = bfs((a0-mean)*rs*g[lane]    + b[lane]);
  hf[base+lane+64] = bfs((a1-mean)*rs*g[lane+64] + b[lane+64]);
}

// ---------------- EdgeUpdate v9: single ea read via wave-private LDS tile ----------------
__global__ __launch_bounds__(256) void k_edge_mfma9(
    const int* __restrict__ src, const int* __restrict__ dst,
    const short* __restrict__ P12, const float* __restrict__ ea,
    const short* __restrict__ Wmep,
    const float* __restrict__ eg, const float* __restrict__ ebv,
    float* __restrict__ out){
  __shared__ float eas[4][32*68];
  const int tid = threadIdx.x, lane = tid & 63, wid = tid >> 6;
  const int l16 = lane & 15, lg = lane >> 4;
  const size_t e0 = (size_t)blockIdx.x*128 + wid*32;
  const int ko = lg*8;
  f32x4 acc[8][2] = {};
  const short8* Bg = ((const short8*)Wmep) + lane;
  float* myl = eas[wid];

  short8 p1v[2][4], p2v[2][4];
#pragma unroll
  for(int mi=0;mi<2;mi++)
#pragma unroll
    for(int r=0;r<4;r++){
      size_t erow = e0 + mi*16 + lg*4 + r;
      int sE = src[erow], dE = dst[erow];
      p1v[mi][r] = *(const short8*)(P12 + (size_t)sE*256 + l16*8);
      p2v[mi][r] = *(const short8*)(P12 + (size_t)dE*256 + 128 + l16*8);
    }

#pragma unroll
  for(int kc=0; kc<2; kc++){
    short8 a[2];
#pragma unroll
    for(int mi=0;mi<2;mi++){
      const float* ap = ea + (e0 + mi*16 + l16)*64 + kc*32 + ko;
      float4 f0 = *(const float4*)ap;
      float4 f1 = *(const float4*)(ap+4);
      float* lp = &myl[(mi*16 + l16)*68 + kc*32 + ko];
      *(float4*)lp     = f0;
      *(float4*)(lp+4) = f1;
      a[mi][0]=bfs(f0.x); a[mi][1]=bfs(f0.y); a[mi][2]=bfs(f0.z); a[mi][3]=bfs(f0.w);
      a[mi][4]=bfs(f1.x); a[mi][5]=bfs(f1.y); a[mi][6]=bfs(f1.z); a[mi][7]=bfs(f1.w);
    }
#pragma unroll
    for(int cf=0;cf<8;cf++){
      short8 b = Bg[(kc*8+cf)*64];
      acc[cf][0] = __builtin_amdgcn_mfma_f32_16x16x32_bf16(a[0], b, acc[cf][0], 0, 0, 0);
      acc[cf][1] = __builtin_amdgcn_mfma_f32_16x16x32_bf16(a[1], b, acc[cf][1], 0, 0, 0);
    }
  }

#pragma unroll
  for(int mi=0;mi<2;mi++)
#pragma unroll
    for(int r=0;r<4;r++)
#pragma unroll
      for(int cf=0;cf<8;cf++)
        acc[cf][mi][r] += bf2f(p1v[mi][r][cf]) + bf2f(p2v[mi][r][cf]);

  float eav[2][4][4];
#pragma unroll
  for(int mi=0;mi<2;mi++)
#pragma unroll
    for(int r=0;r<4;r++)
#pragma unroll
      for(int cf=0;cf<4;cf++)
        eav[mi][r][cf] = myl[(mi*16 + lg*4 + r)*68 + cf*16 + l16];

  float egc[4], ebc[4];
#pragma unroll
  for(int cf=0;cf<4;cf++){
    int col = cf*16 + l16;
    egc[cf] = eg[col];
    ebc[cf] = ebv[col];
  }
#pragma unroll
  for(int mi=0;mi<2;mi++){
#pragma unroll
    for(int r=0;r<4;r++){
      size_t erow = e0 + mi*16 + lg*4 + r;
      float u[4];
      float s1 = 0.f, s2 = 0.f;
#pragma unroll
      for(int cf=0;cf<4;cf++){
        float dlt = fmaxf(0.f, acc[cf][mi][r]);
        float gt  = fmaxf(0.f, acc[cf+4][mi][r]);
        float sig = __builtin_amdgcn_rcpf(1.f + __expf(-gt));
        float uu = eav[mi][r][cf] + dlt * sig;
        u[cf] = uu; s1 += uu; s2 += uu*uu;
      }
#pragma unroll
      for(int off=1; off<16; off<<=1){
        s1 += __shfl_xor(s1, off, 64);
        s2 += __shfl_xor(s2, off, 64);
      }
      float mean = s1 * (1.f/64.f);
      float var  = s2 * (1.f/64.f) - mean*mean;
      float rs = rsqrtf(var + 1e-5f);
#pragma unroll
      for(int cf=0;cf<4;cf++)
        out[erow*64 + cf*16 + l16] = (u[cf]-mean)*rs*egc[cf] + ebc[cf];
    }
  }
}

extern "C" void kernel_launch(void* const* d_in, const int* in_sizes, int n_in,
                              void* d_out, int out_size, void* d_ws, size_t ws_size,
                              hipStream_t stream){
  const float* x       = (const float*)d_in[0];
  const int*   eidx    = (const int*)d_in[1];
  const float* eattr   = (const float*)d_in[2];
  const float* deg_emb = (const float*)d_in[3];
  const float* ln_g = (const float*)d_in[4];
  const float* ln_b = (const float*)d_in[5];
  const float* Wq = (const float*)d_in[6];  const float* bq = (const float*)d_in[7];
  const float* Wk = (const float*)d_in[8];  const float* bk = (const float*)d_in[9];
  const float* Wv = (const float*)d_in[10]; const float* bv = (const float*)d_in[11];
  const float* We = (const float*)d_in[12]; const float* be = (const float*)d_in[13];
  const float* Ws = (const float*)d_in[14]; const float* bs = (const float*)d_in[15];
  const float* W1 = (const float*)d_in[16]; const float* b1 = (const float*)d_in[17];
  const float* W2 = (const float*)d_in[18]; const float* b2 = (const float*)d_in[19];
  const float* eug = (const float*)d_in[20]; const float* eub = (const float*)d_in[21];
  const float* Wm = (const float*)d_in[22]; const float* bm = (const float*)d_in[23];
  const float* eg = (const float*)d_in[24]; const float* eb = (const float*)d_in[25];
  (void)in_sizes; (void)n_in; (void)out_size; (void)ws_size;

  const int* src = eidx;
  const int* dst = eidx + N_EDGES;

  float* ws = (float*)d_ws;
  size_t o = 0;
  auto alloc = [&](size_t n){ size_t r = o; o += (n + 63) & ~(size_t)63; return r; };
  size_t o_deg   = alloc(N_NODES);                 // int, memset
  size_t o_hist  = alloc(N_NODES);                 // int, memset
  size_t zero_f  = o;
  size_t o_rows  = alloc(N_NODES+1);               // int
  size_t o_cur   = alloc(N_NODES);                 // int
  size_t o_invp  = alloc(N_EDGES);                 // int: natural -> sorted position
  size_t o_ssrc  = alloc(N_EDGES);                 // int
  size_t o_attn  = alloc((size_t)N_NODES*D);       // x_attn f32
  size_t o_xin   = alloc((size_t)N_NODES*D);       // x_in f32; xn(bf16) reuses later
  size_t o_h     = alloc((size_t)N_NODES*D/2);     // h bf16 -> hf bf16
  size_t o_qkv16 = alloc((size_t)N_NODES*256);     // qkvs bf16 [N,512]; t1 reuses
  size_t o_p12   = alloc((size_t)N_NODES*128);     // P12 bf16 [N,256]
  size_t o_wcat  = alloc((size_t)D*4*D);
  size_t o_bcat  = alloc(4*D);
  size_t o_bmcat = alloc(256);
  size_t o_wqp   = alloc((size_t)128*512/2);
  size_t o_w1p   = alloc((size_t)128*512/2);
  size_t o_w2p   = alloc((size_t)512*128/2);
  size_t o_wm12  = alloc((size_t)256*128/2);       // Wm[0:256] packed
  size_t o_wmep  = alloc((size_t)64*128/2);        // Wm[256:320] packed
  size_t o_wep   = alloc((size_t)64*128/2);        // We packed

  float* xnew_out = (float*)d_out;                          // [N,128]
  float* ea_out   = xnew_out + (size_t)N_NODES*D;           // [E,64]
  short* es = (short*)ea_out;                               // sorted interleaved e-proj

  hipMemsetAsync(d_ws, 0, zero_f*sizeof(float), stream);

  k_deg<<<(N_EDGES+255)/256, 256, 0, stream>>>(src, dst, (int*)(ws+o_deg),
                                               (int*)(ws+o_hist));
  k_scan<<<1, 1024, 0, stream>>>((int*)(ws+o_hist), (int*)(ws+o_rows),
                                 (int*)(ws+o_cur));
  k_scatter<<<(N_EDGES+255)/256, 256, 0, stream>>>(src, dst, (int*)(ws+o_cur),
                                                   (int*)(ws+o_invp),
                                                   (int*)(ws+o_ssrc));
  k_node_prep<<<N_NODES/4, 256, 0, stream>>>(x, (int*)(ws+o_deg), deg_emb, ln_g, ln_b,
                                             ws+o_xin, (short*)(ws+o_h));
  k_pack<<<(D*4*D + 4*D + 255)/256, 256, 0, stream>>>(Wq,Wk,Wv,Ws, bq,bk,bv,bs,
                                                      ws+o_wcat, ws+o_bcat);
  k_bmcat<<<1, 256, 0, stream>>>(bm, ws+o_bmcat);
  k_packWN<<<256, 256, 0, stream>>>(ws+o_wcat, (short*)(ws+o_wqp), 128, 512);
  k_packWN<<<256, 256, 0, stream>>>(W1, (short*)(ws+o_w1p), 128, 512);
  k_packWN<<<256, 256, 0, stream>>>(W2, (short*)(ws+o_w2p), 512, 128);
  k_packWm12<<<128, 256, 0, stream>>>(Wm, (short*)(ws+o_wm12));
  k_packWN<<<32,  256, 0, stream>>>(Wm + 256*128, (short*)(ws+o_wmep), 64, 128);
  k_packWN<<<32,  256, 0, stream>>>(We, (short*)(ws+o_wep), 64, 128);
  {
    dim3 g((N_NODES+63)/64, 4);    // qkvs = bf16(h @ Wcat + bcat), interleaved store
    k_gemm_mfma<0,1,__hip_bfloat16,short><<<g,256,0,stream>>>(
        (const short*)(ws+o_h), (const short*)(ws+o_wqp), ws+o_bcat,
        (__hip_bfloat16*)(ws+o_qkv16), N_NODES, 128, 512);
  }
  k_eproj_nat<<<N_EDGES/64, 256, 0, stream>>>(eattr, (const int*)(ws+o_invp),
                                              (const short*)(ws+o_wep), be,
                                              (int*)es);
  k_attn_fused3<<<(N_NODES+3)/4, 256, 0, stream>>>((const int*)(ws+o_ssrc),
                                                   (int*)(ws+o_rows),
                                                   (const short*)(ws+o_qkv16), es,
                                                   ws+o_xin, ln_g, ln_b,
                                                   ws+o_attn, (short*)(ws+o_h));
  {
    dim3 g((N_NODES+63)/64, 4);    // t1 = bf16(gelu(hf @ W1 + b1)), natural store
    k_gemm_mfma<1,0,__hip_bfloat16,short><<<g,256,0,stream>>>(
        (const short*)(ws+o_h), (const short*)(ws+o_w1p), b1,
        (__hip_bfloat16*)(ws+o_qkv16), N_NODES, 128, 512);
  }
  {
    dim3 g((N_NODES+63)/64);       // x_new + fused eu-LN -> xn bf16 (o_xin)
    k_ffn2_ln<<<g,256,0,stream>>>(
        (const short*)(ws+o_qkv16), (const short*)(ws+o_w2p), b2, ws+o_attn,
        eug, eub, xnew_out, (short*)(ws+o_xin), N_NODES);
  }
  {
    dim3 g((N_NODES+63)/64, 2);    // P12 = bf16(xn @ [Wm_src|Wm_dst] + bmcat), fragment layout
    k_gemm_mfma<0,2,__hip_bfloat16,short><<<g,256,0,stream>>>(
        (const short*)(ws+o_xin), (const short*)(ws+o_wm12), ws+o_bmcat,
        (__hip_bfloat16*)(ws+o_p12), N_NODES, 128, 256);
  }
  k_edge_mfma9<<<N_EDGES/128, 256, 0, stream>>>(src, dst, (const short*)(ws+o_p12),
                                                eattr, (const short*)(ws+o_wmep),
                                                eg, eb, ea_out);
}